// Round 1
// baseline (32306.677 us; speedup 1.0000x reference)
//
#include <hip/hip_runtime.h>
#include <stdint.h>

// LSTMModel: 4-layer LSTM (B=256,T=512,H=256,Din=28) + sigmoid proj (21)
// Strategy: persistent wavefront-pipelined kernel, 256 WGs (1/CU), hand-rolled
// per-step grid barrier, bf16 MFMA 16x16x32, weights resident in LDS,
// gate rows reordered n' = 4*j + gate so cell update is WG-local.

#define B 256
#define T 512
#define H 256
#define DIN 28
#define NLAYER 4
#define NWG 256
#define NSTEP (T + NLAYER - 1)   // 515
#define OUTD 21

typedef __attribute__((ext_vector_type(8))) __bf16 bf16x8;
typedef __attribute__((ext_vector_type(4))) float f32x4;
typedef __attribute__((ext_vector_type(4))) unsigned short u16x4;

// ---- workspace layout (bytes) ----
#define WS_CNT   0ull                                        // 515 barrier slots * 128B
#define WS_HBUF  71680ull                                    // [l][par][b][j] bf16: 4*2*256*256*2 = 1 MiB
#define WS_CST   (WS_HBUF + 4ull*2*B*H*2)                    // c state f32 [l][b][j]: 1 MiB
#define WS_H3F   (WS_CST + 4ull*B*H*4)                       // layer-3 last h, f32 [b][j]: 256 KiB
#define WS_XBF   (WS_H3F + (unsigned long long)B*H*4)        // x bf16 [b][t][32] (28 padded): 8 MiB
#define WS_WIH0  (WS_XBF + (unsigned long long)B*T*32*2)     // W_ih layer0 reordered [n'][32] bf16
#define WS_WIHR  (WS_WIH0 + 1024ull*32*2)                    // W_ih layers1-3 reordered [l-1][n'][256] bf16
#define WS_WHHR  (WS_WIHR + 3ull*1024*256*2)                 // W_hh reordered [l][n'][256] bf16
#define WS_BIAS  (WS_WHHR + 4ull*1024*256*2)                 // b_ih+b_hh f32 [l][n']
#define WS_ZERO  WS_XBF                                      // zero prefix each launch

__device__ __forceinline__ unsigned short f2bf(float f) {
  unsigned u = __builtin_bit_cast(unsigned, f);
  u += 0x7fffu + ((u >> 16) & 1u);          // round-to-nearest-even
  return (unsigned short)(u >> 16);
}
__device__ __forceinline__ float sigf(float x) { return 1.f / (1.f + __expf(-x)); }
__device__ __forceinline__ float tanhfast(float x) {
  float e = __expf(2.f * x);
  return 1.f - 2.f / (e + 1.f);
}
__device__ __forceinline__ bf16x8 ldb8(const void* p) { return *(const bf16x8*)p; }

// ---------------- prep kernels ----------------
__global__ void prep_x(const float* __restrict__ x, unsigned short* __restrict__ xbf) {
  int tot = B * T * 32;
  for (int idx = blockIdx.x * blockDim.x + threadIdx.x; idx < tot;
       idx += gridDim.x * blockDim.x) {
    int kk = idx & 31;
    int bt = idx >> 5;
    float v = (kk < DIN) ? x[(size_t)bt * DIN + kk] : 0.f;
    xbf[idx] = f2bf(v);
  }
}

__global__ void prep_w(const float* __restrict__ wih0, const float* __restrict__ wihrest,
                       const float* __restrict__ whh, const float* __restrict__ bih,
                       const float* __restrict__ bhh,
                       unsigned short* __restrict__ wih0r, unsigned short* __restrict__ wihr,
                       unsigned short* __restrict__ whhr, float* __restrict__ biasr) {
  const int R0 = 1024 * 32, R1 = 3 * 1024 * 256, R2 = 4 * 1024 * 256, R3 = 4 * 1024;
  int tot = R0 + R1 + R2 + R3;
  for (int idx = blockIdx.x * blockDim.x + threadIdx.x; idx < tot;
       idx += gridDim.x * blockDim.x) {
    if (idx < R0) {
      int k = idx & 31, np = idx >> 5, g = np & 3, j = np >> 2;
      wih0r[idx] = f2bf(k < DIN ? wih0[(size_t)(g * 256 + j) * DIN + k] : 0.f);
    } else if (idx < R0 + R1) {
      int i = idx - R0;
      int k = i & 255, r = i >> 8, np = r & 1023, l = r >> 10, g = np & 3, j = np >> 2;
      wihr[i] = f2bf(wihrest[((size_t)l * 1024 + g * 256 + j) * 256 + k]);
    } else if (idx < R0 + R1 + R2) {
      int i = idx - R0 - R1;
      int k = i & 255, r = i >> 8, np = r & 1023, l = r >> 10, g = np & 3, j = np >> 2;
      whhr[i] = f2bf(whh[((size_t)l * 1024 + g * 256 + j) * 256 + k]);
    } else {
      int i = idx - R0 - R1 - R2;
      int np = i & 1023, l = i >> 10, g = np & 3, j = np >> 2;
      biasr[i] = bih[l * 1024 + g * 256 + j] + bhh[l * 1024 + g * 256 + j];
    }
  }
}

// ---------------- main persistent kernel ----------------
template <int ASTRIDE>
__device__ __forceinline__ void kstep(const unsigned short* aptr, int akbase, int wkcol,
                                      const unsigned char* Ws, int arow0, int arow1,
                                      int akoff, int brow0, int brow1, f32x4& a00,
                                      f32x4& a01, f32x4& a10, f32x4& a11) {
  bf16x8 a0 = ldb8(aptr + (size_t)arow0 * ASTRIDE + akbase + akoff);
  bf16x8 a1 = ldb8(aptr + (size_t)arow1 * ASTRIDE + akbase + akoff);
  int kb = (wkcol + akoff) * 2;
  bf16x8 b0 = ldb8(Ws + brow0 * 1024 + (kb ^ ((brow0 & 7) << 4)));
  bf16x8 b1 = ldb8(Ws + brow1 * 1024 + (kb ^ ((brow1 & 7) << 4)));
  a00 = __builtin_amdgcn_mfma_f32_16x16x32_bf16(a0, b0, a00, 0, 0, 0);
  a01 = __builtin_amdgcn_mfma_f32_16x16x32_bf16(a0, b1, a01, 0, 0, 0);
  a10 = __builtin_amdgcn_mfma_f32_16x16x32_bf16(a1, b0, a10, 0, 0, 0);
  a11 = __builtin_amdgcn_mfma_f32_16x16x32_bf16(a1, b1, a11, 0, 0, 0);
}

__launch_bounds__(256, 1)
__global__ void lstm_main(const unsigned short* __restrict__ xbf,
                          const unsigned short* __restrict__ wih0r,
                          const unsigned short* __restrict__ wihr,
                          const unsigned short* __restrict__ whhr,
                          const float* __restrict__ biasr,
                          const float* __restrict__ Wout, const float* __restrict__ bout,
                          unsigned short* __restrict__ hbuf, float* __restrict__ cst,
                          float* __restrict__ h3f, unsigned* __restrict__ cnt,
                          float* __restrict__ out) {
  __shared__ unsigned char Ws[64 * 1024];   // 64 weight rows x 1KB (512 bf16), XOR-swizzled
  __shared__ float gates[64 * 68];          // [n'rel][brel] exchange buffer, stride 68

  const int tid = threadIdx.x;
  const int lane = tid & 63;
  const int w = tid >> 6;
  const int wb = w >> 1, wn = w & 1;
  const int bid = blockIdx.x;
  const int layer = (bid & 7) >> 1;               // 2 XCDs per layer
  const int wgl = ((bid >> 3) << 1) | (bid & 1);  // 0..63 within layer
  const int b0 = (wgl >> 4) * 64;
  const int ntile = wgl & 15;
  const int n0 = ntile * 64;   // n' base (n' = 4j+g)
  const int j0 = ntile * 16;

  // ---- load resident weight slice into LDS (once) ----
  const int ngr = (layer == 0) ? 36 : 64;  // 16B granules per row
  for (int i = tid; i < 64 * ngr; i += 256) {
    int row = i / ngr, blk = i % ngr;
    uint4 v;
    if (layer == 0) {
      if (blk < 4) v = *(const uint4*)(wih0r + (size_t)(n0 + row) * 32 + blk * 8);
      else v = *(const uint4*)(whhr + (size_t)(n0 + row) * 256 + (blk - 4) * 8);
    } else {
      if (blk < 32)
        v = *(const uint4*)(wihr + ((size_t)(layer - 1) * 1024 + n0 + row) * 256 + blk * 8);
      else
        v = *(const uint4*)(whhr + ((size_t)layer * 1024 + n0 + row) * 256 + (blk - 32) * 8);
    }
    *(uint4*)(Ws + row * 1024 + ((blk * 16) ^ ((row & 7) << 4))) = v;
  }
  const float bv0 = biasr[layer * 1024 + n0 + wn * 32 + (lane & 15)];
  const float bv1 = biasr[layer * 1024 + n0 + wn * 32 + 16 + (lane & 15)];
  __syncthreads();

  const int arow0 = b0 + wb * 32 + (lane & 15);
  const int arow1 = arow0 + 16;
  const int akoff = (lane >> 4) * 8;
  const int brow0 = wn * 32 + (lane & 15);
  const int brow1 = brow0 + 16;

  for (int s = 0; s < NSTEP; ++s) {
    const int t = s - layer;
    const bool active = (t >= 0) && (t < T);
    if (active) {
      const int par = t & 1;
      f32x4 a00 = {bv0, bv0, bv0, bv0};
      f32x4 a01 = {bv1, bv1, bv1, bv1};
      f32x4 a10 = a00, a11 = a01;
      const unsigned short* hbR = hbuf + ((size_t)layer * 2 + (par ^ 1)) * 65536;
      if (layer == 0) {
        kstep<16384>(xbf + t * 32, 0, 0, Ws, arow0, arow1, akoff, brow0, brow1,
                     a00, a01, a10, a11);
#pragma unroll
        for (int ki = 1; ki < 9; ++ki)
          kstep<256>(hbR, (ki - 1) * 32, ki * 32, Ws, arow0, arow1, akoff, brow0, brow1,
                     a00, a01, a10, a11);
      } else {
        const unsigned short* hbP = hbuf + ((size_t)(layer - 1) * 2 + par) * 65536;
#pragma unroll
        for (int ki = 0; ki < 8; ++ki)
          kstep<256>(hbP, ki * 32, ki * 32, Ws, arow0, arow1, akoff, brow0, brow1,
                     a00, a01, a10, a11);
#pragma unroll
        for (int ki = 8; ki < 16; ++ki)
          kstep<256>(hbR, (ki - 8) * 32, ki * 32, Ws, arow0, arow1, akoff, brow0, brow1,
                     a00, a01, a10, a11);
      }
      // scatter acc frags to LDS: gates[n'rel][brel]
      {
        int c = lane & 15, Rg = lane >> 4;
        *(f32x4*)&gates[(wn * 32 + c) * 68 + wb * 32 + Rg * 4] = a00;
        *(f32x4*)&gates[(wn * 32 + 16 + c) * 68 + wb * 32 + Rg * 4] = a01;
        *(f32x4*)&gates[(wn * 32 + c) * 68 + wb * 32 + 16 + Rg * 4] = a10;
        *(f32x4*)&gates[(wn * 32 + 16 + c) * 68 + wb * 32 + 16 + Rg * 4] = a11;
      }
      __syncthreads();
      {
        int brel = tid & 63, jq = tid >> 6;
        int b = b0 + brel;
        int jb = j0 + jq * 4;
        float* cp = &cst[((size_t)layer * B + b) * H + jb];
        f32x4 cold = *(f32x4*)cp;
        f32x4 cnew;
        float hv[4];
#pragma unroll
        for (int i2 = 0; i2 < 4; ++i2) {
          int jr = jq * 4 + i2;
          float ip = gates[(4 * jr + 0) * 68 + brel];
          float fp = gates[(4 * jr + 1) * 68 + brel];
          float gp = gates[(4 * jr + 2) * 68 + brel];
          float op = gates[(4 * jr + 3) * 68 + brel];
          float ii = sigf(ip), ff = sigf(fp), gg = tanhfast(gp), oo = sigf(op);
          float cc = ff * cold[i2] + ii * gg;
          cnew[i2] = cc;
          hv[i2] = oo * tanhfast(cc);
        }
        *(f32x4*)cp = cnew;
        u16x4 h4 = {f2bf(hv[0]), f2bf(hv[1]), f2bf(hv[2]), f2bf(hv[3])};
        *(u16x4*)(hbuf + ((size_t)layer * 2 + par) * 65536 + (size_t)b * H + jb) = h4;
        if (layer == 3 && t == T - 1) {
          f32x4 hf = {hv[0], hv[1], hv[2], hv[3]};
          *(f32x4*)&h3f[(size_t)b * H + jb] = hf;
        }
      }
    }
    // ---- grid barrier (per-step counter) ----
    __syncthreads();
    __threadfence();
    if (tid == 0) {
      unsigned* c = cnt + (size_t)s * 32;
      __hip_atomic_fetch_add(c, 1u, __ATOMIC_RELEASE, __HIP_MEMORY_SCOPE_AGENT);
      while (__hip_atomic_load(c, __ATOMIC_ACQUIRE, __HIP_MEMORY_SCOPE_AGENT) < NWG)
        __builtin_amdgcn_s_sleep(1);
    }
    __syncthreads();
    __threadfence();
  }

  // ---- final projection: out[b][o] = sigmoid(h3 . Wout[o] + bout[o]) ----
  {
    int b = bid;
    if (tid < OUTD) {
      const float* wr = Wout + (size_t)tid * H;
      const float* hr = h3f + (size_t)b * H;
      float sum = bout[tid];
      for (int j = 0; j < H; ++j) sum = fmaf(hr[j], wr[j], sum);
      out[b * OUTD + tid] = sigf(sum);
    }
  }
}

extern "C" void kernel_launch(void* const* d_in, const int* in_sizes, int n_in,
                              void* d_out, int out_size, void* d_ws, size_t ws_size,
                              hipStream_t stream) {
  const float* x = (const float*)d_in[0];
  const float* Wih0 = (const float*)d_in[1];
  const float* WihRest = (const float*)d_in[2];
  const float* Whh = (const float*)d_in[3];
  const float* bih = (const float*)d_in[4];
  const float* bhh = (const float*)d_in[5];
  const float* Wout = (const float*)d_in[6];
  const float* bout = (const float*)d_in[7];
  float* out = (float*)d_out;
  char* ws = (char*)d_ws;

  unsigned* cnt = (unsigned*)(ws + WS_CNT);
  unsigned short* hbuf = (unsigned short*)(ws + WS_HBUF);
  float* cst = (float*)(ws + WS_CST);
  float* h3f = (float*)(ws + WS_H3F);
  unsigned short* xbf = (unsigned short*)(ws + WS_XBF);
  unsigned short* wih0r = (unsigned short*)(ws + WS_WIH0);
  unsigned short* wihr = (unsigned short*)(ws + WS_WIHR);
  unsigned short* whhr = (unsigned short*)(ws + WS_WHHR);
  float* biasr = (float*)(ws + WS_BIAS);

  hipMemsetAsync(ws, 0, (size_t)WS_ZERO, stream);
  prep_x<<<2048, 256, 0, stream>>>(x, xbf);
  prep_w<<<2048, 256, 0, stream>>>(Wih0, WihRest, Whh, bih, bhh, wih0r, wihr, whhr, biasr);
  lstm_main<<<NWG, 256, 0, stream>>>(xbf, wih0r, wihr, whhr, biasr, Wout, bout, hbuf,
                                     cst, h3f, cnt, out);
}

// Round 2
// 5366.768 us; speedup vs baseline: 6.0198x; 6.0198x over previous
//
#include <hip/hip_runtime.h>
#include <stdint.h>

// LSTMModel: 4-layer LSTM (B=256,T=512,H=256,Din=28) + sigmoid proj (21)
// R2: replace global barrier (+threadfence L2 flush/inv storms) with
// fine-grained dataflow flags. All cross-WG data via relaxed agent-scope
// atomics (write-through to MALL, no cache maintenance). c-state in regs.

#define B 256
#define T 512
#define H 256
#define DIN 28
#define NWG 256
#define OUTD 21

typedef __attribute__((ext_vector_type(8))) __bf16 bf16x8;
typedef __attribute__((ext_vector_type(4))) float f32x4;
typedef __attribute__((ext_vector_type(4))) unsigned short u16x4;
typedef unsigned long long u64;

// ---- workspace layout (bytes) ----
#define WS_FLAGS 0ull                                   // 4*4*512 u32 = 32 KB
#define WS_HBUF  32768ull                               // [l][par][b][j] bf16: 4*2*256*256*2 = 1 MiB
#define WS_H3F   (WS_HBUF + 4ull*2*B*H*2)               // layer-3 last h, f32 [b][j]: 256 KiB
#define WS_XBF   (WS_H3F + (u64)B*H*4)                  // x bf16 [b][t][32]: 8 MiB
#define WS_WIH0  (WS_XBF + (u64)B*T*32*2)               // W_ih layer0 reordered [n'][32] bf16
#define WS_WIHR  (WS_WIH0 + 1024ull*32*2)               // W_ih layers1-3 reordered
#define WS_WHHR  (WS_WIHR + 3ull*1024*256*2)            // W_hh reordered
#define WS_BIAS  (WS_WHHR + 4ull*1024*256*2)            // b_ih+b_hh f32 [l][n']
#define WS_ZERO  WS_H3F                                 // zero flags + hbuf each launch

#define FIDX(l, g, t) (((((l)*4) + (g)) << 9) | (t))

__device__ __forceinline__ unsigned short f2bf(float f) {
  unsigned u = __builtin_bit_cast(unsigned, f);
  u += 0x7fffu + ((u >> 16) & 1u);
  return (unsigned short)(u >> 16);
}
__device__ __forceinline__ float sigf(float x) { return 1.f / (1.f + __expf(-x)); }
__device__ __forceinline__ float tanhfast(float x) {
  float e = __expf(2.f * x);
  return 1.f - 2.f / (e + 1.f);
}
__device__ __forceinline__ bf16x8 ldb8(const void* p) { return *(const bf16x8*)p; }

// coherent (agent-scope, cache-bypassing) 16B load / 8B store — no fences
__device__ __forceinline__ bf16x8 ldg_coh16(const unsigned short* p) {
  union { u64 q[2]; bf16x8 v; } u;
  u.q[0] = __hip_atomic_load((const u64*)p, __ATOMIC_RELAXED, __HIP_MEMORY_SCOPE_AGENT);
  u.q[1] = __hip_atomic_load((const u64*)p + 1, __ATOMIC_RELAXED, __HIP_MEMORY_SCOPE_AGENT);
  return u.v;
}
__device__ __forceinline__ void stg_coh8(void* p, u64 v) {
  __hip_atomic_store((u64*)p, v, __ATOMIC_RELAXED, __HIP_MEMORY_SCOPE_AGENT);
}
__device__ __forceinline__ unsigned ldflag(const unsigned* f) {
  return __hip_atomic_load(f, __ATOMIC_RELAXED, __HIP_MEMORY_SCOPE_AGENT);
}

// ---------------- prep kernels ----------------
__global__ void prep_x(const float* __restrict__ x, unsigned short* __restrict__ xbf) {
  int tot = B * T * 32;
  for (int idx = blockIdx.x * blockDim.x + threadIdx.x; idx < tot;
       idx += gridDim.x * blockDim.x) {
    int kk = idx & 31;
    int bt = idx >> 5;
    float v = (kk < DIN) ? x[(size_t)bt * DIN + kk] : 0.f;
    xbf[idx] = f2bf(v);
  }
}

__global__ void prep_w(const float* __restrict__ wih0, const float* __restrict__ wihrest,
                       const float* __restrict__ whh, const float* __restrict__ bih,
                       const float* __restrict__ bhh,
                       unsigned short* __restrict__ wih0r, unsigned short* __restrict__ wihr,
                       unsigned short* __restrict__ whhr, float* __restrict__ biasr) {
  const int R0 = 1024 * 32, R1 = 3 * 1024 * 256, R2 = 4 * 1024 * 256, R3 = 4 * 1024;
  int tot = R0 + R1 + R2 + R3;
  for (int idx = blockIdx.x * blockDim.x + threadIdx.x; idx < tot;
       idx += gridDim.x * blockDim.x) {
    if (idx < R0) {
      int k = idx & 31, np = idx >> 5, g = np & 3, j = np >> 2;
      wih0r[idx] = f2bf(k < DIN ? wih0[(size_t)(g * 256 + j) * DIN + k] : 0.f);
    } else if (idx < R0 + R1) {
      int i = idx - R0;
      int k = i & 255, r = i >> 8, np = r & 1023, l = r >> 10, g = np & 3, j = np >> 2;
      wihr[i] = f2bf(wihrest[((size_t)l * 1024 + g * 256 + j) * 256 + k]);
    } else if (idx < R0 + R1 + R2) {
      int i = idx - R0 - R1;
      int k = i & 255, r = i >> 8, np = r & 1023, l = r >> 10, g = np & 3, j = np >> 2;
      whhr[i] = f2bf(whh[((size_t)l * 1024 + g * 256 + j) * 256 + k]);
    } else {
      int i = idx - R0 - R1 - R2;
      int np = i & 1023, l = i >> 10, g = np & 3, j = np >> 2;
      biasr[i] = bih[l * 1024 + g * 256 + j] + bhh[l * 1024 + g * 256 + j];
    }
  }
}

// ---------------- main persistent kernel ----------------
template <int ASTRIDE, bool COH>
__device__ __forceinline__ void kstep(const unsigned short* aptr, int akbase, int wkcol,
                                      const unsigned char* Ws, int arow0, int arow1,
                                      int akoff, int brow0, int brow1, f32x4& a00,
                                      f32x4& a01, f32x4& a10, f32x4& a11) {
  bf16x8 a0, a1;
  if (COH) {
    a0 = ldg_coh16(aptr + (size_t)arow0 * ASTRIDE + akbase + akoff);
    a1 = ldg_coh16(aptr + (size_t)arow1 * ASTRIDE + akbase + akoff);
  } else {
    a0 = ldb8(aptr + (size_t)arow0 * ASTRIDE + akbase + akoff);
    a1 = ldb8(aptr + (size_t)arow1 * ASTRIDE + akbase + akoff);
  }
  int kb = (wkcol + akoff) * 2;
  bf16x8 b0 = ldb8(Ws + brow0 * 1024 + (kb ^ ((brow0 & 7) << 4)));
  bf16x8 b1 = ldb8(Ws + brow1 * 1024 + (kb ^ ((brow1 & 7) << 4)));
  a00 = __builtin_amdgcn_mfma_f32_16x16x32_bf16(a0, b0, a00, 0, 0, 0);
  a01 = __builtin_amdgcn_mfma_f32_16x16x32_bf16(a0, b1, a01, 0, 0, 0);
  a10 = __builtin_amdgcn_mfma_f32_16x16x32_bf16(a1, b0, a10, 0, 0, 0);
  a11 = __builtin_amdgcn_mfma_f32_16x16x32_bf16(a1, b1, a11, 0, 0, 0);
}

__launch_bounds__(256, 1)
__global__ void lstm_main(const unsigned short* __restrict__ xbf,
                          const unsigned short* __restrict__ wih0r,
                          const unsigned short* __restrict__ wihr,
                          const unsigned short* __restrict__ whhr,
                          const float* __restrict__ biasr,
                          const float* __restrict__ Wout, const float* __restrict__ bout,
                          unsigned short* __restrict__ hbuf, float* __restrict__ h3f,
                          unsigned* __restrict__ flags, float* __restrict__ out) {
  __shared__ unsigned char Ws[64 * 1024];   // 64 weight rows x 1KB, XOR-swizzled
  __shared__ float gates[64 * 68];          // [n'rel][brel] exchange, stride 68

  const int tid = threadIdx.x;
  const int lane = tid & 63;
  const int w = tid >> 6;
  const int wb = w >> 1, wn = w & 1;
  const int bid = blockIdx.x;
  const int layer = (bid & 7) >> 1;               // 2 XCDs per layer
  const int wgl = ((bid >> 3) << 1) | (bid & 1);  // 0..63 within layer
  const int b0g = wgl >> 4;                       // b0 group 0..3
  const int b0 = b0g * 64;
  const int ntile = wgl & 15;
  const int n0 = ntile * 64;
  const int j0 = ntile * 16;

  // ---- load resident weight slice into LDS (once) ----
  const int ngr = (layer == 0) ? 36 : 64;
  for (int i = tid; i < 64 * ngr; i += 256) {
    int row = i / ngr, blk = i % ngr;
    uint4 v;
    if (layer == 0) {
      if (blk < 4) v = *(const uint4*)(wih0r + (size_t)(n0 + row) * 32 + blk * 8);
      else v = *(const uint4*)(whhr + (size_t)(n0 + row) * 256 + (blk - 4) * 8);
    } else {
      if (blk < 32)
        v = *(const uint4*)(wihr + ((size_t)(layer - 1) * 1024 + n0 + row) * 256 + blk * 8);
      else
        v = *(const uint4*)(whhr + ((size_t)layer * 1024 + n0 + row) * 256 + (blk - 32) * 8);
    }
    *(uint4*)(Ws + row * 1024 + ((blk * 16) ^ ((row & 7) << 4))) = v;
  }
  const float bv0 = biasr[layer * 1024 + n0 + wn * 32 + (lane & 15)];
  const float bv1 = biasr[layer * 1024 + n0 + wn * 32 + 16 + (lane & 15)];
  __syncthreads();

  const int arow0 = b0 + wb * 32 + (lane & 15);
  const int arow1 = arow0 + 16;
  const int akoff = (lane >> 4) * 8;
  const int brow0 = wn * 32 + (lane & 15);
  const int brow1 = brow0 + 16;

  // cell state in registers: thread (brel=tid&63, jq=tid>>6) owns b0+brel, j0+jq*4+0..3
  f32x4 creg = {0.f, 0.f, 0.f, 0.f};

  for (int t = 0; t < T; ++t) {
    // ---- dataflow wait: rec(t-1), prev-layer(t), back-pressure(t-2) ----
    {
      const unsigned* frec = (t > 0) ? &flags[FIDX(layer, b0g, t - 1)] : nullptr;
      const unsigned* fprev = (layer > 0) ? &flags[FIDX(layer - 1, b0g, t)] : nullptr;
      const unsigned* fdown = (layer < 3 && t >= 2) ? &flags[FIDX(layer + 1, b0g, t - 2)] : nullptr;
      for (;;) {
        unsigned a = frec ? ldflag(frec) : 16u;
        unsigned b = fprev ? ldflag(fprev) : 16u;
        unsigned c = fdown ? ldflag(fdown) : 16u;
        if (a >= 16u && b >= 16u && c >= 16u) break;
        __builtin_amdgcn_s_sleep(2);
      }
      asm volatile("" ::: "memory");
    }

    const int par = t & 1;
    f32x4 a00 = {bv0, bv0, bv0, bv0};
    f32x4 a01 = {bv1, bv1, bv1, bv1};
    f32x4 a10 = a00, a11 = a01;
    const unsigned short* hbR = hbuf + ((size_t)layer * 2 + (par ^ 1)) * 65536;
    if (layer == 0) {
      kstep<16384, false>(xbf + t * 32, 0, 0, Ws, arow0, arow1, akoff, brow0, brow1,
                          a00, a01, a10, a11);
#pragma unroll
      for (int ki = 1; ki < 9; ++ki)
        kstep<256, true>(hbR, (ki - 1) * 32, ki * 32, Ws, arow0, arow1, akoff, brow0,
                         brow1, a00, a01, a10, a11);
    } else {
      const unsigned short* hbP = hbuf + ((size_t)(layer - 1) * 2 + par) * 65536;
#pragma unroll
      for (int ki = 0; ki < 8; ++ki)
        kstep<256, true>(hbP, ki * 32, ki * 32, Ws, arow0, arow1, akoff, brow0, brow1,
                         a00, a01, a10, a11);
#pragma unroll
      for (int ki = 8; ki < 16; ++ki)
        kstep<256, true>(hbR, (ki - 8) * 32, ki * 32, Ws, arow0, arow1, akoff, brow0,
                         brow1, a00, a01, a10, a11);
    }
    // scatter acc frags to LDS: gates[n'rel][brel]
    {
      int c = lane & 15, Rg = lane >> 4;
      *(f32x4*)&gates[(wn * 32 + c) * 68 + wb * 32 + Rg * 4] = a00;
      *(f32x4*)&gates[(wn * 32 + 16 + c) * 68 + wb * 32 + Rg * 4] = a01;
      *(f32x4*)&gates[(wn * 32 + c) * 68 + wb * 32 + 16 + Rg * 4] = a10;
      *(f32x4*)&gates[(wn * 32 + 16 + c) * 68 + wb * 32 + 16 + Rg * 4] = a11;
    }
    __syncthreads();
    // activations + cell update (c in regs) + coherent h store
    {
      int brel = tid & 63, jq = tid >> 6;
      int b = b0 + brel;
      int jb = j0 + jq * 4;
      f32x4 cnew;
      float hv[4];
#pragma unroll
      for (int i2 = 0; i2 < 4; ++i2) {
        int jr = jq * 4 + i2;
        float ip = gates[(4 * jr + 0) * 68 + brel];
        float fp = gates[(4 * jr + 1) * 68 + brel];
        float gp = gates[(4 * jr + 2) * 68 + brel];
        float op = gates[(4 * jr + 3) * 68 + brel];
        float ii = sigf(ip), ff = sigf(fp), gg = tanhfast(gp), oo = sigf(op);
        float cc = ff * creg[i2] + ii * gg;
        cnew[i2] = cc;
        hv[i2] = oo * tanhfast(cc);
      }
      creg = cnew;
      u16x4 h4 = {f2bf(hv[0]), f2bf(hv[1]), f2bf(hv[2]), f2bf(hv[3])};
      stg_coh8(hbuf + ((size_t)layer * 2 + par) * 65536 + (size_t)b * H + jb,
               __builtin_bit_cast(u64, h4));
      if (layer == 3 && t == T - 1) {
        float2 p01 = make_float2(hv[0], hv[1]);
        float2 p23 = make_float2(hv[2], hv[3]);
        stg_coh8(h3f + (size_t)b * H + jb, __builtin_bit_cast(u64, p01));
        stg_coh8(h3f + (size_t)b * H + jb + 2, __builtin_bit_cast(u64, p23));
      }
    }
    // drain write-through stores, then publish flag (no cache maintenance)
    asm volatile("s_waitcnt vmcnt(0)" ::: "memory");
    __syncthreads();
    if (tid == 0)
      __hip_atomic_fetch_add(&flags[FIDX(layer, b0g, t)], 1u, __ATOMIC_RELAXED,
                             __HIP_MEMORY_SCOPE_AGENT);
  }

  // ---- final projection by layer-3 WGs: 4 b each ----
  if (layer == 3) {
    while (ldflag(&flags[FIDX(3, b0g, T - 1)]) < 16u) __builtin_amdgcn_s_sleep(2);
    asm volatile("" ::: "memory");
    // stage h3f[4 b][256] f32 into LDS (reuse gates: 4 rows, stride 260)
    for (int i = tid; i < 4 * 128; i += 256) {
      int bi = i >> 7, jj = (i & 127) * 2;
      u64 q = __hip_atomic_load(
          (const u64*)(h3f + (size_t)(b0 + ntile * 4 + bi) * H + jj), __ATOMIC_RELAXED,
          __HIP_MEMORY_SCOPE_AGENT);
      float2 hf = __builtin_bit_cast(float2, q);
      gates[bi * 260 + jj] = hf.x;
      gates[bi * 260 + jj + 1] = hf.y;
    }
    __syncthreads();
    if (tid < 4 * OUTD) {
      int o = tid % OUTD, bi = tid / OUTD;
      int b = b0 + ntile * 4 + bi;
      const float* wr = Wout + (size_t)o * H;
      const float* hr = &gates[bi * 260];
      float sum = bout[o];
#pragma unroll 8
      for (int j = 0; j < H; ++j) sum = fmaf(hr[j], wr[j], sum);
      out[b * OUTD + o] = sigf(sum);
    }
  }
}

extern "C" void kernel_launch(void* const* d_in, const int* in_sizes, int n_in,
                              void* d_out, int out_size, void* d_ws, size_t ws_size,
                              hipStream_t stream) {
  const float* x = (const float*)d_in[0];
  const float* Wih0 = (const float*)d_in[1];
  const float* WihRest = (const float*)d_in[2];
  const float* Whh = (const float*)d_in[3];
  const float* bih = (const float*)d_in[4];
  const float* bhh = (const float*)d_in[5];
  const float* Wout = (const float*)d_in[6];
  const float* bout = (const float*)d_in[7];
  float* out = (float*)d_out;
  char* ws = (char*)d_ws;

  unsigned* flags = (unsigned*)(ws + WS_FLAGS);
  unsigned short* hbuf = (unsigned short*)(ws + WS_HBUF);
  float* h3f = (float*)(ws + WS_H3F);
  unsigned short* xbf = (unsigned short*)(ws + WS_XBF);
  unsigned short* wih0r = (unsigned short*)(ws + WS_WIH0);
  unsigned short* wihr = (unsigned short*)(ws + WS_WIHR);
  unsigned short* whhr = (unsigned short*)(ws + WS_WHHR);
  float* biasr = (float*)(ws + WS_BIAS);

  hipMemsetAsync(ws, 0, (size_t)WS_ZERO, stream);
  prep_x<<<2048, 256, 0, stream>>>(x, xbf);
  prep_w<<<2048, 256, 0, stream>>>(Wih0, WihRest, Whh, bih, bhh, wih0r, wihr, whhr, biasr);
  lstm_main<<<NWG, 256, 0, stream>>>(xbf, wih0r, wihr, whhr, biasr, Wout, bout, hbuf,
                                     h3f, flags, out);
}